// Round 17
// baseline (232.901 us; speedup 1.0000x reference)
//
#include <hip/hip_runtime.h>
#include <hip/hip_fp16.h>
#include <math.h>

#define N_NODES 100000
#define F 32
#define BUCKET 64
#define NB ((N_NODES + BUCKET - 1) / BUCKET)   // 1563
#define NBLK 128                                // chunks for hist/scatter passes
#define SMAX 1536                               // per-bucket sort capacity

// ---------------- pass 1: per-chunk bucket histogram (LDS, 1024 thr) ----------------
__global__ void hist_kernel(const int* __restrict__ col, int* __restrict__ counts, int E) {
    __shared__ int hist[NB];
    int tid = threadIdx.x, blk = blockIdx.x;
    for (int i = tid; i < NB; i += 1024) hist[i] = 0;
    __syncthreads();
    int chunk = (E + NBLK - 1) / NBLK;
    int beg = blk * chunk;
    int end = beg + chunk; if (end > E) end = E;
    for (int e = beg + tid; e < end; e += 1024) atomicAdd(&hist[col[e] >> 6], 1);
    __syncthreads();
    for (int i = tid; i < NB; i += 1024) counts[(size_t)blk * NB + i] = hist[i];
}

// ---------------- pass 2a-pre: bucket totals (coalesced) ----------------
__global__ void tot_kernel(const int* __restrict__ counts, int* __restrict__ tot) {
    int b = blockIdx.x * 256 + threadIdx.x;
    if (b >= NB) return;
    int s = 0;
    for (int blk = 0; blk < NBLK; blk++) s += counts[(size_t)blk * NB + b];
    tot[b] = s;
}

// ---------------- pass 2a: exclusive scan of bucket totals (1 block, 6KB read) ----------------
__global__ void offA_kernel(const int* __restrict__ tot, int* __restrict__ bucket_base,
                            int* __restrict__ rowstart) {
    __shared__ int psum[1024];
    int tid = threadIdx.x;
    int b0 = 2 * tid, b1 = 2 * tid + 1;
    int t0 = (b0 < NB) ? tot[b0] : 0;
    int t1 = (b1 < NB) ? tot[b1] : 0;
    int s = t0 + t1;
    psum[tid] = s;
    __syncthreads();
    for (int off = 1; off < 1024; off <<= 1) {
        int v = (tid >= off) ? psum[tid - off] : 0;
        __syncthreads();
        psum[tid] += v;
        __syncthreads();
    }
    int excl = psum[tid] - s;
    if (b0 < NB) bucket_base[b0] = excl;
    if (b1 < NB) bucket_base[b1] = excl + t0;
    if (tid == 1023) { bucket_base[NB] = psum[1023]; rowstart[N_NODES] = psum[1023]; }
}

// ---------------- pass 2b: per-(chunk,bucket) offsets, coalesced ----------------
__global__ void offB_kernel(const int* __restrict__ counts, const int* __restrict__ bucket_base,
                            int* __restrict__ boff) {
    int b = blockIdx.x * 256 + threadIdx.x;
    if (b >= NB) return;
    int running = bucket_base[b];
    for (int blk = 0; blk < NBLK; blk++) {
        boff[(size_t)blk * NB + b] = running;
        running += counts[(size_t)blk * NB + b];
    }
}

// ---------------- pass 3: scatter into bucket-grouped storage (LDS cursors, 1024 thr) ----------------
__global__ void scatter_kernel(const int* __restrict__ row, const int* __restrict__ col,
                               const int* __restrict__ boff, unsigned* __restrict__ storage, int E) {
    __shared__ int cur[NB];
    int tid = threadIdx.x, blk = blockIdx.x;
    for (int i = tid; i < NB; i += 1024) cur[i] = boff[(size_t)blk * NB + i];
    __syncthreads();
    int chunk = (E + NBLK - 1) / NBLK;
    int beg = blk * chunk;
    int end = beg + chunk; if (end > E) end = E;
    for (int e = beg + tid; e < end; e += 1024) {
        int c = col[e], r = row[e];
        int pos = atomicAdd(&cur[c >> 6], 1);       // LDS atomic, block-owned segment
        storage[pos] = ((unsigned)(c & 63) << 17) | (unsigned)r;
    }
}

// ---------------- per-bucket LDS counting sort -> CSR + dis + xd ----------------
__global__ void csr_build_kernel(const unsigned* __restrict__ storage, const int* __restrict__ bucket_base,
                                 int* __restrict__ rowstart, int* __restrict__ csr_src,
                                 float* __restrict__ dis, const float* __restrict__ x,
                                 float* __restrict__ xd, int n) {
    __shared__ unsigned sh[SMAX];
    __shared__ int outloc[SMAX];
    __shared__ int hist[BUCKET];
    __shared__ int pre[BUCKET];
    __shared__ int cur[BUCKET];
    __shared__ float dloc[BUCKET];
    int b = blockIdx.x, tid = threadIdx.x;
    if (tid < BUCKET) hist[tid] = 0;
    __syncthreads();
    int base = bucket_base[b];
    int tot = bucket_base[b + 1] - base;
    if (tot > SMAX) tot = SMAX;
    for (int i = tid; i < tot; i += 256) sh[i] = storage[base + i];
    __syncthreads();
    for (int i = tid; i < tot; i += 256) atomicAdd(&hist[sh[i] >> 17], 1);
    __syncthreads();
    if (tid < BUCKET) pre[tid] = hist[tid];
    __syncthreads();
    for (int off = 1; off < BUCKET; off <<= 1) {
        int v = 0;
        if (tid < BUCKET && tid >= off) v = pre[tid - off];
        __syncthreads();
        if (tid < BUCKET && tid >= off) pre[tid] += v;
        __syncthreads();
    }
    if (tid < BUCKET) {
        int excl = pre[tid] - hist[tid];
        cur[tid] = excl;
        int node = b * BUCKET + tid;
        if (node < n) {
            rowstart[node] = base + excl;
            int d = hist[tid];
            float dv = (d > 0) ? rsqrtf((float)d) : 0.0f;
            dis[node] = dv;
            dloc[tid] = dv;
        }
    }
    __syncthreads();
    for (int i = tid; i < BUCKET * 8; i += 256) {
        int nl = i >> 3, f = i & 7;
        int node = b * BUCKET + nl;
        if (node < n) xd[(size_t)node * 8 + f] = (f < 5) ? dloc[nl] * x[(size_t)node * 5 + f] : 0.0f;
    }
    for (int i = tid; i < tot; i += 256) {
        unsigned p = sh[i];
        int pos = atomicAdd(&cur[p >> 17], 1);
        outloc[pos] = (int)(p & 0x1FFFF);
    }
    __syncthreads();
    for (int i = tid; i < tot; i += 256) csr_src[base + i] = outloc[i];
}

// ---------------- layer 1 fused: gather xd (8 lanes/node) + W1 transform -> gd_a fp16 ----------------
__global__ void layer1_fused(const float* __restrict__ xd, const int* __restrict__ rowstart,
                             const int* __restrict__ csr_src, const float* __restrict__ dis,
                             const float* __restrict__ W1, const float* __restrict__ b1,
                             __half* __restrict__ gda, int n) {
    __shared__ float Ws[5 * F];
    __shared__ float s1s[32][8];
    int tid = threadIdx.x;
    if (tid < 5 * F) Ws[tid] = W1[tid];
    int grp = tid >> 3, f = tid & 7;
    int node = blockIdx.x * 32 + grp;
    float sum = 0.0f;
    if (node < n) {
        int start = rowstart[node], end = rowstart[node + 1];
        float a0 = 0, a1 = 0, a2 = 0, a3 = 0, a4 = 0, a5 = 0, a6 = 0, a7 = 0;
        int i = start;
        for (; i + 7 < end; i += 8) {
            int r0 = csr_src[i], r1 = csr_src[i+1], r2 = csr_src[i+2], r3 = csr_src[i+3];
            int r4 = csr_src[i+4], r5 = csr_src[i+5], r6 = csr_src[i+6], r7 = csr_src[i+7];
            a0 += xd[r0*8+f]; a1 += xd[r1*8+f]; a2 += xd[r2*8+f]; a3 += xd[r3*8+f];
            a4 += xd[r4*8+f]; a5 += xd[r5*8+f]; a6 += xd[r6*8+f]; a7 += xd[r7*8+f];
        }
        for (; i < end; i++) a0 += xd[csr_src[i]*8+f];
        sum = ((a0+a1)+(a2+a3)) + ((a4+a5)+(a6+a7));
    }
    s1s[grp][f] = sum;
    __syncthreads();
    if (node < n) {
        float dv = dis[node];
        float sk0 = dv * s1s[grp][0], sk1 = dv * s1s[grp][1], sk2 = dv * s1s[grp][2];
        float sk3 = dv * s1s[grp][3], sk4 = dv * s1s[grp][4];
        int fb = f * 4;
#pragma unroll
        for (int j = 0; j < 4; j++) {
            int ff = fb + j;
            float acc = b1[ff] + sk0 * Ws[0*F+ff] + sk1 * Ws[1*F+ff] + sk2 * Ws[2*F+ff]
                       + sk3 * Ws[3*F+ff] + sk4 * Ws[4*F+ff];
            float h = acc > 0.0f ? acc : 0.0f;
            gda[(size_t)node * F + ff] = __float2half(dv * h);
        }
    }
}

// ======== 4-lane gather core: lane l holds features 8l..8l+7 (one uint4 = 16B/row) ========
// Coalesced idx loads (lane l reads csr_src[i+l]) + width-4 shfl broadcast + prefetch.
__device__ __forceinline__ void gather4lane(const uint4* __restrict__ gin4,
                                            const int* __restrict__ csr_src,
                                            int start, int end, int l, int E,
                                            float a[8]) {
#pragma unroll
    for (int j = 0; j < 8; j++) a[j] = 0.0f;
    int i = start;
    if (i + 4 <= end) {
        int safe = i + l; if (safe > E - 1) safe = E - 1;
        int myidx = csr_src[safe];
        while (i + 4 <= end) {
            int nexti = i + 4;
            int nextidx = 0;
            if (nexti + 4 <= end) {
                int s2 = nexti + l; if (s2 > E - 1) s2 = E - 1;
                nextidx = csr_src[s2];                 // prefetch next chunk's indices
            }
#pragma unroll
            for (int j = 0; j < 4; j++) {
                int r = __shfl(myidx, j, 4);
                uint4 v = gin4[(size_t)r * 4 + l];
                float2 f0 = __half22float2(*(__half2*)&v.x);
                float2 f1 = __half22float2(*(__half2*)&v.y);
                float2 f2 = __half22float2(*(__half2*)&v.z);
                float2 f3 = __half22float2(*(__half2*)&v.w);
                a[0] += f0.x; a[1] += f0.y; a[2] += f1.x; a[3] += f1.y;
                a[4] += f2.x; a[5] += f2.y; a[6] += f3.x; a[7] += f3.y;
            }
            myidx = nextidx;
            i = nexti;
        }
    }
    for (; i < end; i++) {
        int r = csr_src[i];
        uint4 v = gin4[(size_t)r * 4 + l];
        float2 f0 = __half22float2(*(__half2*)&v.x);
        float2 f1 = __half22float2(*(__half2*)&v.y);
        float2 f2 = __half22float2(*(__half2*)&v.z);
        float2 f3 = __half22float2(*(__half2*)&v.w);
        a[0] += f0.x; a[1] += f0.y; a[2] += f1.x; a[3] += f1.y;
        a[4] += f2.x; a[5] += f2.y; a[6] += f3.x; a[7] += f3.y;
    }
}

// ---------------- fused mid layer: 4 lanes/node, 64 nodes/block ----------------
__global__ void layer_mid_fused(const uint4* __restrict__ gin4, const int* __restrict__ rowstart,
                                const int* __restrict__ csr_src, const float* __restrict__ dis,
                                const float* __restrict__ W, const float* __restrict__ bb,
                                uint4* __restrict__ gout4, int n, int E) {
    __shared__ float Ws[F * F];
    __shared__ float hs[64][F + 1];
    int tid = threadIdx.x;
    for (int i = tid; i < F * F; i += 256) Ws[i] = W[i];
    int grp = tid >> 2;
    int l = tid & 3;
    int node = blockIdx.x * 64 + grp;
    float dv = 0.0f;
    float a[8];
    if (node < n) {
        int start = rowstart[node], end = rowstart[node + 1];
        gather4lane(gin4, csr_src, start, end, l, E, a);
        dv = dis[node];
        int fb = 8 * l;
#pragma unroll
        for (int j = 0; j < 8; j++) hs[grp][fb + j] = dv * a[j];
    }
    __syncthreads();
    if (node < n) {
        int fb = 8 * l;
        float acc[8];
#pragma unroll
        for (int j = 0; j < 8; j++) acc[j] = bb[fb + j];
#pragma unroll
        for (int k = 0; k < F; k++) {
            float hv = hs[grp][k];
#pragma unroll
            for (int j = 0; j < 8; j++) acc[j] += hv * Ws[k*F + fb + j];
        }
        __half2 o0 = __floats2half2_rn(dv * (acc[0] > 0.0f ? acc[0] : 0.0f),
                                       dv * (acc[1] > 0.0f ? acc[1] : 0.0f));
        __half2 o1 = __floats2half2_rn(dv * (acc[2] > 0.0f ? acc[2] : 0.0f),
                                       dv * (acc[3] > 0.0f ? acc[3] : 0.0f));
        __half2 o2 = __floats2half2_rn(dv * (acc[4] > 0.0f ? acc[4] : 0.0f),
                                       dv * (acc[5] > 0.0f ? acc[5] : 0.0f));
        __half2 o3 = __floats2half2_rn(dv * (acc[6] > 0.0f ? acc[6] : 0.0f),
                                       dv * (acc[7] > 0.0f ? acc[7] : 0.0f));
        uint4 pack;
        pack.x = *(unsigned*)&o0;
        pack.y = *(unsigned*)&o1;
        pack.z = *(unsigned*)&o2;
        pack.w = *(unsigned*)&o3;
        gout4[(size_t)node * 4 + l] = pack;
    }
}

// ---------------- fused last layer: 4 lanes/node + heads + argmax partials ----------------
__global__ void layer_last_fused(const uint4* __restrict__ gin4, const int* __restrict__ rowstart,
                                 const int* __restrict__ csr_src, const float* __restrict__ dis,
                                 const float* __restrict__ W3, const float* __restrict__ b3,
                                 const float* __restrict__ Wd, const float* __restrict__ bd,
                                 const float* __restrict__ Wa, const float* __restrict__ ba,
                                 float* __restrict__ out, float* __restrict__ pmax,
                                 int* __restrict__ pidx, int n, int E) {
    __shared__ float Ws[F * F];
    __shared__ float hs[64][F + 1];
    __shared__ float gmax[64];
    __shared__ int gidx[64];
    int tid = threadIdx.x;
    for (int i = tid; i < F * F; i += 256) Ws[i] = W3[i];
    int grp = tid >> 2;
    int l = tid & 3;
    int node = blockIdx.x * 64 + grp;
    float dv = 0.0f;
    float a[8];
    if (node < n) {
        int start = rowstart[node], end = rowstart[node + 1];
        gather4lane(gin4, csr_src, start, end, l, E, a);
        dv = dis[node];
        int fb = 8 * l;
#pragma unroll
        for (int j = 0; j < 8; j++) hs[grp][fb + j] = dv * a[j];
    }
    __syncthreads();
    if (node < n) {
        int fb = 8 * l;
        float acc[8];
#pragma unroll
        for (int j = 0; j < 8; j++) acc[j] = b3[fb + j];
#pragma unroll
        for (int k = 0; k < F; k++) {
            float hv = hs[grp][k];
#pragma unroll
            for (int j = 0; j < 8; j++) acc[j] += hv * Ws[k*F + fb + j];
        }
        float dterm = 0.0f, aterm = 0.0f;
#pragma unroll
        for (int j = 0; j < 8; j++) {
            float h = acc[j] > 0.0f ? acc[j] : 0.0f;
            dterm += h * Wd[fb + j];
            aterm += h * Wa[fb + j];
        }
#pragma unroll
        for (int off = 2; off > 0; off >>= 1) {
            dterm += __shfl_xor(dterm, off, 4);
            aterm += __shfl_xor(aterm, off, 4);
        }
        if (l == 0) {
            out[node] = dterm + bd[0];
            float asc = aterm + ba[0];
            out[N_NODES + node] = asc;
            gmax[grp] = asc;
            gidx[grp] = node;
        }
    } else if (l == 0) {
        gmax[grp] = -INFINITY;
        gidx[grp] = 0x7fffffff;
    }
    __syncthreads();
    if (tid == 0) {
        float best = gmax[0]; int bi = gidx[0];
        for (int g = 1; g < 64; g++) {
            if (gmax[g] > best || (gmax[g] == best && gidx[g] < bi)) { best = gmax[g]; bi = gidx[g]; }
        }
        pmax[blockIdx.x] = best;
        pidx[blockIdx.x] = bi;
    }
}

// ---------------- final: argmax, re-gather target row from gd_b (fp16), tail heads ----------------
__global__ void final_kernel(const float* __restrict__ pmax, const int* __restrict__ pidx, int nblocks,
                             const __half* __restrict__ gin, const int* __restrict__ rowstart,
                             const int* __restrict__ csr_src, const float* __restrict__ dis,
                             const float* __restrict__ W3, const float* __restrict__ b3,
                             const float* __restrict__ Wt, const float* __restrict__ bt,
                             const float* __restrict__ Wact, const float* __restrict__ bact,
                             float* __restrict__ out) {
    __shared__ float smax[256];
    __shared__ int sidx[256];
    __shared__ float part[8][F];
    __shared__ float hrow[F];
    __shared__ float ht[F];
    int tid = threadIdx.x;
    float best = -INFINITY; int bi = 0x7fffffff;
    for (int i = tid; i < nblocks; i += 256) {
        float v = pmax[i]; int ix = pidx[i];
        if (v > best || (v == best && ix < bi)) { best = v; bi = ix; }
    }
    smax[tid] = best; sidx[tid] = bi;
    __syncthreads();
    for (int st = 128; st > 0; st >>= 1) {
        if (tid < st) {
            float v2 = smax[tid + st]; int i2 = sidx[tid + st];
            if (v2 > smax[tid] || (v2 == smax[tid] && i2 < sidx[tid])) { smax[tid] = v2; sidx[tid] = i2; }
        }
        __syncthreads();
    }
    int target = sidx[0];
    int g = tid >> 5, f = tid & 31;
    int start = rowstart[target], end = rowstart[target + 1];
    float acc = 0.0f;
    for (int i = start + g; i < end; i += 8)
        acc += __half2float(gin[(size_t)csr_src[i] * F + f]);
    part[g][f] = acc;
    __syncthreads();
    if (tid < F) {
        float s = 0.0f;
#pragma unroll
        for (int gg = 0; gg < 8; gg++) s += part[gg][tid];
        hrow[tid] = dis[target] * s;
    }
    __syncthreads();
    if (tid < F) {
        float a = b3[tid];
#pragma unroll
        for (int k = 0; k < F; k++) a += hrow[k] * W3[k*F+tid];
        ht[tid] = a > 0.0f ? a : 0.0f;
    }
    __syncthreads();
    if (tid < 2) {
        float a = bt[tid];
#pragma unroll
        for (int k = 0; k < F; k++) a += ht[k] * Wt[k*2+tid];
        out[2 * N_NODES + tid] = a;
    } else if (tid < 11) {
        int j = tid - 2;
        float a = bact[j];
#pragma unroll
        for (int k = 0; k < F; k++) a += ht[k] * Wact[k*9+j];
        out[2 * N_NODES + 2 + j] = a;
    }
}

extern "C" void kernel_launch(void* const* d_in, const int* in_sizes, int n_in,
                              void* d_out, int out_size, void* d_ws, size_t ws_size,
                              hipStream_t stream) {
    const float* x  = (const float*)d_in[0];
    const int*   ei = (const int*)d_in[1];
    const int E = in_sizes[1] / 2;
    const int* row = ei;
    const int* col = ei + E;
    const float* W1 = (const float*)d_in[2];
    const float* b1 = (const float*)d_in[3];
    const float* W2 = (const float*)d_in[4];
    const float* b2 = (const float*)d_in[5];
    const float* W3 = (const float*)d_in[6];
    const float* b3 = (const float*)d_in[7];
    const float* Wd = (const float*)d_in[8];
    const float* bd = (const float*)d_in[9];
    const float* Wa = (const float*)d_in[10];
    const float* ba = (const float*)d_in[11];
    const float* Wt = (const float*)d_in[12];
    const float* bt = (const float*)d_in[13];
    const float* Wact = (const float*)d_in[14];
    const float* bact = (const float*)d_in[15];

    float* out = (float*)d_out;
    float* ws  = (float*)d_ws;

    // workspace layout (floats):
    //   dis [0,N) | xd [N,9N) | gd_a (half,16N fl) [17N,33N) | gd_b (half,16N fl) [33N,49N)
    //   storage (E u32 <= 16N slots, exact) aliases gd_b; dead before layer_mid writes gd_b
    //   gd_a/gd_b byte offsets: 17N*4=6.8e6, 33N*4=1.32e7 -- both 16B-aligned (uint4 loads ok)
    //   ints from 49N: bucket_base[NB+1] | counts[NBLK*NB] | boff[NBLK*NB] |
    //     rowstart[N+1] | csr_src[E] | pmax[12500] | pidx[12500] | tot[NB]
    float*    dis      = ws;
    float*    xd       = ws + N_NODES;
    __half*   gd_a     = (__half*)(ws + (size_t)17 * N_NODES);
    __half*   gd_b     = (__half*)(ws + (size_t)33 * N_NODES);
    unsigned* storage  = (unsigned*)(ws + (size_t)33 * N_NODES);
    int*      bucket_base = (int*)(ws + (size_t)49 * N_NODES);    // NB+1
    int*      counts   = bucket_base + NB + 1;                    // NBLK*NB = 200064
    int*      boff     = counts + NBLK * NB;                      // 200064
    int*      rowstart = boff + NBLK * NB;                        // N+1
    int*      csr_src  = rowstart + N_NODES + 1;                  // E
    float*    pmax     = (float*)(csr_src + E);                   // 1563 used
    int*      pidx     = (int*)(pmax + 12500);                    // 1563 used
    int*      tot      = pidx + 12500;                            // NB

    const int B = 256;
    const int nb32 = (N_NODES + 31) / 32;          // 3125 (layer1)
    const int nb64 = (N_NODES + 63) / 64;          // 1563 (mid/last, 64 nodes/block)

    // ---- CSR build: 2-pass block-local counting sort, ZERO device atomics ----
    hist_kernel<<<NBLK, 1024, 0, stream>>>(col, counts, E);
    tot_kernel<<<(NB + 255) / 256, B, 0, stream>>>(counts, tot);
    offA_kernel<<<1, 1024, 0, stream>>>(tot, bucket_base, rowstart);
    offB_kernel<<<(NB + 255) / 256, B, 0, stream>>>(counts, bucket_base, boff);
    scatter_kernel<<<NBLK, 1024, 0, stream>>>(row, col, boff, storage, E);
    csr_build_kernel<<<NB, B, 0, stream>>>(storage, bucket_base, rowstart, csr_src, dis, x, xd, N_NODES);

    // ---- layer 1 (fused gather + W1 transform) ----
    layer1_fused<<<nb32, B, 0, stream>>>(xd, rowstart, csr_src, dis, W1, b1, gd_a, N_NODES);

    // ---- layer 2 (fused gather + transform, 4 lanes/node, uint4 rows) ----
    layer_mid_fused<<<nb64, B, 0, stream>>>((const uint4*)gd_a, rowstart, csr_src, dis,
                                            W2, b2, (uint4*)gd_b, N_NODES, E);

    // ---- layer 3 + heads (fused, 4 lanes/node) ----
    layer_last_fused<<<nb64, B, 0, stream>>>((const uint4*)gd_b, rowstart, csr_src, dis,
                                             W3, b3, Wd, bd, Wa, ba, out, pmax, pidx, N_NODES, E);
    final_kernel<<<1, B, 0, stream>>>(pmax, pidx, nb64, gd_b, rowstart, csr_src, dis,
                                      W3, b3, Wt, bt, Wact, bact, out);
}

// Round 18
// 225.082 us; speedup vs baseline: 1.0347x; 1.0347x over previous
//
#include <hip/hip_runtime.h>
#include <hip/hip_fp16.h>
#include <math.h>

// R18 = R16 restore (measured best: 230.4 us). 8-lane gather, BUCKET=64,
// NBLK=128, 1024-thread hist/scatter, zero-device-atomic CSR build,
// fp16 feature tables, fused gather+transform layers.

#define N_NODES 100000
#define F 32
#define BUCKET 64
#define NB ((N_NODES + BUCKET - 1) / BUCKET)   // 1563
#define NBLK 128                                // chunks for hist/scatter passes
#define SMAX 1536                               // per-bucket sort capacity

// ---------------- pass 1: per-chunk bucket histogram (LDS, 1024 thr) ----------------
__global__ void hist_kernel(const int* __restrict__ col, int* __restrict__ counts, int E) {
    __shared__ int hist[NB];
    int tid = threadIdx.x, blk = blockIdx.x;
    for (int i = tid; i < NB; i += 1024) hist[i] = 0;
    __syncthreads();
    int chunk = (E + NBLK - 1) / NBLK;
    int beg = blk * chunk;
    int end = beg + chunk; if (end > E) end = E;
    for (int e = beg + tid; e < end; e += 1024) atomicAdd(&hist[col[e] >> 6], 1);
    __syncthreads();
    for (int i = tid; i < NB; i += 1024) counts[(size_t)blk * NB + i] = hist[i];
}

// ---------------- pass 2a-pre: bucket totals (coalesced) ----------------
__global__ void tot_kernel(const int* __restrict__ counts, int* __restrict__ tot) {
    int b = blockIdx.x * 256 + threadIdx.x;
    if (b >= NB) return;
    int s = 0;
    for (int blk = 0; blk < NBLK; blk++) s += counts[(size_t)blk * NB + b];
    tot[b] = s;
}

// ---------------- pass 2a: exclusive scan of bucket totals (1 block, 6KB read) ----------------
__global__ void offA_kernel(const int* __restrict__ tot, int* __restrict__ bucket_base,
                            int* __restrict__ rowstart) {
    __shared__ int psum[1024];
    int tid = threadIdx.x;
    int b0 = 2 * tid, b1 = 2 * tid + 1;
    int t0 = (b0 < NB) ? tot[b0] : 0;
    int t1 = (b1 < NB) ? tot[b1] : 0;
    int s = t0 + t1;
    psum[tid] = s;
    __syncthreads();
    for (int off = 1; off < 1024; off <<= 1) {
        int v = (tid >= off) ? psum[tid - off] : 0;
        __syncthreads();
        psum[tid] += v;
        __syncthreads();
    }
    int excl = psum[tid] - s;
    if (b0 < NB) bucket_base[b0] = excl;
    if (b1 < NB) bucket_base[b1] = excl + t0;
    if (tid == 1023) { bucket_base[NB] = psum[1023]; rowstart[N_NODES] = psum[1023]; }
}

// ---------------- pass 2b: per-(chunk,bucket) offsets, coalesced ----------------
__global__ void offB_kernel(const int* __restrict__ counts, const int* __restrict__ bucket_base,
                            int* __restrict__ boff) {
    int b = blockIdx.x * 256 + threadIdx.x;
    if (b >= NB) return;
    int running = bucket_base[b];
    for (int blk = 0; blk < NBLK; blk++) {
        boff[(size_t)blk * NB + b] = running;
        running += counts[(size_t)blk * NB + b];
    }
}

// ---------------- pass 3: scatter into bucket-grouped storage (LDS cursors, 1024 thr) ----------------
__global__ void scatter_kernel(const int* __restrict__ row, const int* __restrict__ col,
                               const int* __restrict__ boff, unsigned* __restrict__ storage, int E) {
    __shared__ int cur[NB];
    int tid = threadIdx.x, blk = blockIdx.x;
    for (int i = tid; i < NB; i += 1024) cur[i] = boff[(size_t)blk * NB + i];
    __syncthreads();
    int chunk = (E + NBLK - 1) / NBLK;
    int beg = blk * chunk;
    int end = beg + chunk; if (end > E) end = E;
    for (int e = beg + tid; e < end; e += 1024) {
        int c = col[e], r = row[e];
        int pos = atomicAdd(&cur[c >> 6], 1);       // LDS atomic, block-owned segment
        storage[pos] = ((unsigned)(c & 63) << 17) | (unsigned)r;
    }
}

// ---------------- per-bucket LDS counting sort -> CSR + dis + xd ----------------
__global__ void csr_build_kernel(const unsigned* __restrict__ storage, const int* __restrict__ bucket_base,
                                 int* __restrict__ rowstart, int* __restrict__ csr_src,
                                 float* __restrict__ dis, const float* __restrict__ x,
                                 float* __restrict__ xd, int n) {
    __shared__ unsigned sh[SMAX];
    __shared__ int outloc[SMAX];
    __shared__ int hist[BUCKET];
    __shared__ int pre[BUCKET];
    __shared__ int cur[BUCKET];
    __shared__ float dloc[BUCKET];
    int b = blockIdx.x, tid = threadIdx.x;
    if (tid < BUCKET) hist[tid] = 0;
    __syncthreads();
    int base = bucket_base[b];
    int tot = bucket_base[b + 1] - base;
    if (tot > SMAX) tot = SMAX;
    for (int i = tid; i < tot; i += 256) sh[i] = storage[base + i];
    __syncthreads();
    for (int i = tid; i < tot; i += 256) atomicAdd(&hist[sh[i] >> 17], 1);
    __syncthreads();
    if (tid < BUCKET) pre[tid] = hist[tid];
    __syncthreads();
    for (int off = 1; off < BUCKET; off <<= 1) {
        int v = 0;
        if (tid < BUCKET && tid >= off) v = pre[tid - off];
        __syncthreads();
        if (tid < BUCKET && tid >= off) pre[tid] += v;
        __syncthreads();
    }
    if (tid < BUCKET) {
        int excl = pre[tid] - hist[tid];
        cur[tid] = excl;
        int node = b * BUCKET + tid;
        if (node < n) {
            rowstart[node] = base + excl;
            int d = hist[tid];
            float dv = (d > 0) ? rsqrtf((float)d) : 0.0f;
            dis[node] = dv;
            dloc[tid] = dv;
        }
    }
    __syncthreads();
    for (int i = tid; i < BUCKET * 8; i += 256) {
        int nl = i >> 3, f = i & 7;
        int node = b * BUCKET + nl;
        if (node < n) xd[(size_t)node * 8 + f] = (f < 5) ? dloc[nl] * x[(size_t)node * 5 + f] : 0.0f;
    }
    for (int i = tid; i < tot; i += 256) {
        unsigned p = sh[i];
        int pos = atomicAdd(&cur[p >> 17], 1);
        outloc[pos] = (int)(p & 0x1FFFF);
    }
    __syncthreads();
    for (int i = tid; i < tot; i += 256) csr_src[base + i] = outloc[i];
}

// ---------------- layer 1 fused: gather xd (8 lanes/node) + W1 transform -> gd_a fp16 ----------------
__global__ void layer1_fused(const float* __restrict__ xd, const int* __restrict__ rowstart,
                             const int* __restrict__ csr_src, const float* __restrict__ dis,
                             const float* __restrict__ W1, const float* __restrict__ b1,
                             __half* __restrict__ gda, int n) {
    __shared__ float Ws[5 * F];
    __shared__ float s1s[32][8];
    int tid = threadIdx.x;
    if (tid < 5 * F) Ws[tid] = W1[tid];
    int grp = tid >> 3, f = tid & 7;
    int node = blockIdx.x * 32 + grp;
    float sum = 0.0f;
    if (node < n) {
        int start = rowstart[node], end = rowstart[node + 1];
        float a0 = 0, a1 = 0, a2 = 0, a3 = 0, a4 = 0, a5 = 0, a6 = 0, a7 = 0;
        int i = start;
        for (; i + 7 < end; i += 8) {
            int r0 = csr_src[i], r1 = csr_src[i+1], r2 = csr_src[i+2], r3 = csr_src[i+3];
            int r4 = csr_src[i+4], r5 = csr_src[i+5], r6 = csr_src[i+6], r7 = csr_src[i+7];
            a0 += xd[r0*8+f]; a1 += xd[r1*8+f]; a2 += xd[r2*8+f]; a3 += xd[r3*8+f];
            a4 += xd[r4*8+f]; a5 += xd[r5*8+f]; a6 += xd[r6*8+f]; a7 += xd[r7*8+f];
        }
        for (; i < end; i++) a0 += xd[csr_src[i]*8+f];
        sum = ((a0+a1)+(a2+a3)) + ((a4+a5)+(a6+a7));
    }
    s1s[grp][f] = sum;
    __syncthreads();
    if (node < n) {
        float dv = dis[node];
        float sk0 = dv * s1s[grp][0], sk1 = dv * s1s[grp][1], sk2 = dv * s1s[grp][2];
        float sk3 = dv * s1s[grp][3], sk4 = dv * s1s[grp][4];
        int fb = f * 4;
#pragma unroll
        for (int j = 0; j < 4; j++) {
            int ff = fb + j;
            float acc = b1[ff] + sk0 * Ws[0*F+ff] + sk1 * Ws[1*F+ff] + sk2 * Ws[2*F+ff]
                       + sk3 * Ws[3*F+ff] + sk4 * Ws[4*F+ff];
            float h = acc > 0.0f ? acc : 0.0f;
            gda[(size_t)node * F + ff] = __float2half(dv * h);
        }
    }
}

// ======== 8-lane gather core: lane l holds features 4l..4l+3, idx-shfl + prefetch ========
__device__ __forceinline__ void gather8lane(const uint2* __restrict__ gin2,
                                            const int* __restrict__ csr_src,
                                            int start, int end, int l, int E,
                                            float& a0, float& a1, float& a2, float& a3) {
    a0 = a1 = a2 = a3 = 0.0f;
    int i = start;
    if (i + 8 <= end) {
        int safe = i + l; if (safe > E - 1) safe = E - 1;
        int myidx = csr_src[safe];
        while (i + 8 <= end) {
            int nexti = i + 8;
            int nextidx = 0;
            if (nexti + 8 <= end) {
                int s2 = nexti + l; if (s2 > E - 1) s2 = E - 1;
                nextidx = csr_src[s2];                 // prefetch next chunk's indices
            }
#pragma unroll
            for (int j = 0; j < 8; j++) {
                int r = __shfl(myidx, j, 8);
                uint2 v = gin2[(size_t)r * 8 + l];
                __half2 h0 = *(__half2*)&v.x;
                __half2 h1 = *(__half2*)&v.y;
                float2 f0 = __half22float2(h0);
                float2 f1 = __half22float2(h1);
                a0 += f0.x; a1 += f0.y; a2 += f1.x; a3 += f1.y;
            }
            myidx = nextidx;
            i = nexti;
        }
    }
    for (; i < end; i++) {
        int r = csr_src[i];
        uint2 v = gin2[(size_t)r * 8 + l];
        __half2 h0 = *(__half2*)&v.x;
        __half2 h1 = *(__half2*)&v.y;
        float2 f0 = __half22float2(h0);
        float2 f1 = __half22float2(h1);
        a0 += f0.x; a1 += f0.y; a2 += f1.x; a3 += f1.y;
    }
}

// ---------------- fused mid layer: 8 lanes/node, 32 nodes/block ----------------
__global__ void layer_mid_fused(const uint2* __restrict__ gin2, const int* __restrict__ rowstart,
                                const int* __restrict__ csr_src, const float* __restrict__ dis,
                                const float* __restrict__ W, const float* __restrict__ bb,
                                uint2* __restrict__ gout2, int n, int E) {
    __shared__ float Ws[F * F];
    __shared__ float hs[32][F + 1];
    int tid = threadIdx.x;
    for (int i = tid; i < F * F; i += 256) Ws[i] = W[i];
    int grp = tid >> 3;
    int l = tid & 7;
    int node = blockIdx.x * 32 + grp;          // n = 100000 = 3125*32, no partial blocks
    int start = rowstart[node], end = rowstart[node + 1];
    float a0, a1, a2, a3;
    gather8lane(gin2, csr_src, start, end, l, E, a0, a1, a2, a3);
    float dv = dis[node];
    int fb = 4 * l;
    hs[grp][fb]     = dv * a0;
    hs[grp][fb + 1] = dv * a1;
    hs[grp][fb + 2] = dv * a2;
    hs[grp][fb + 3] = dv * a3;
    __syncthreads();
    float acc0 = bb[fb], acc1 = bb[fb+1], acc2 = bb[fb+2], acc3 = bb[fb+3];
#pragma unroll
    for (int k = 0; k < F; k++) {
        float hv = hs[grp][k];
        acc0 += hv * Ws[k*F+fb];
        acc1 += hv * Ws[k*F+fb+1];
        acc2 += hv * Ws[k*F+fb+2];
        acc3 += hv * Ws[k*F+fb+3];
    }
    float h0 = acc0 > 0.0f ? acc0 : 0.0f;
    float h1 = acc1 > 0.0f ? acc1 : 0.0f;
    float h2 = acc2 > 0.0f ? acc2 : 0.0f;
    float h3 = acc3 > 0.0f ? acc3 : 0.0f;
    __half2 o0 = __floats2half2_rn(dv * h0, dv * h1);
    __half2 o1 = __floats2half2_rn(dv * h2, dv * h3);
    uint2 pack;
    pack.x = *(unsigned*)&o0;
    pack.y = *(unsigned*)&o1;
    gout2[(size_t)node * 8 + l] = pack;
}

// ---------------- fused last layer: 8 lanes/node + heads + argmax partials ----------------
__global__ void layer_last_fused(const uint2* __restrict__ gin2, const int* __restrict__ rowstart,
                                 const int* __restrict__ csr_src, const float* __restrict__ dis,
                                 const float* __restrict__ W3, const float* __restrict__ b3,
                                 const float* __restrict__ Wd, const float* __restrict__ bd,
                                 const float* __restrict__ Wa, const float* __restrict__ ba,
                                 float* __restrict__ out, float* __restrict__ pmax,
                                 int* __restrict__ pidx, int n, int E) {
    __shared__ float Ws[F * F];
    __shared__ float hs[32][F + 1];
    __shared__ float gmax[32];
    __shared__ int gidx[32];
    int tid = threadIdx.x;
    for (int i = tid; i < F * F; i += 256) Ws[i] = W3[i];
    int grp = tid >> 3;
    int l = tid & 7;
    int node = blockIdx.x * 32 + grp;
    int start = rowstart[node], end = rowstart[node + 1];
    float a0, a1, a2, a3;
    gather8lane(gin2, csr_src, start, end, l, E, a0, a1, a2, a3);
    float dv = dis[node];
    int fb = 4 * l;
    hs[grp][fb]     = dv * a0;
    hs[grp][fb + 1] = dv * a1;
    hs[grp][fb + 2] = dv * a2;
    hs[grp][fb + 3] = dv * a3;
    __syncthreads();
    float acc0 = b3[fb], acc1 = b3[fb+1], acc2 = b3[fb+2], acc3 = b3[fb+3];
#pragma unroll
    for (int k = 0; k < F; k++) {
        float hv = hs[grp][k];
        acc0 += hv * Ws[k*F+fb];
        acc1 += hv * Ws[k*F+fb+1];
        acc2 += hv * Ws[k*F+fb+2];
        acc3 += hv * Ws[k*F+fb+3];
    }
    float h0 = acc0 > 0.0f ? acc0 : 0.0f;
    float h1 = acc1 > 0.0f ? acc1 : 0.0f;
    float h2 = acc2 > 0.0f ? acc2 : 0.0f;
    float h3 = acc3 > 0.0f ? acc3 : 0.0f;
    float dterm = h0 * Wd[fb] + h1 * Wd[fb+1] + h2 * Wd[fb+2] + h3 * Wd[fb+3];
    float aterm = h0 * Wa[fb] + h1 * Wa[fb+1] + h2 * Wa[fb+2] + h3 * Wa[fb+3];
#pragma unroll
    for (int off = 4; off > 0; off >>= 1) {
        dterm += __shfl_xor(dterm, off, 8);
        aterm += __shfl_xor(aterm, off, 8);
    }
    if (l == 0) {
        out[node] = dterm + bd[0];
        float asc = aterm + ba[0];
        out[N_NODES + node] = asc;
        gmax[grp] = asc;
        gidx[grp] = node;
    }
    __syncthreads();
    if (tid == 0) {
        float best = gmax[0]; int bi = gidx[0];
        for (int g = 1; g < 32; g++) {
            if (gmax[g] > best || (gmax[g] == best && gidx[g] < bi)) { best = gmax[g]; bi = gidx[g]; }
        }
        pmax[blockIdx.x] = best;
        pidx[blockIdx.x] = bi;
    }
}

// ---------------- final: argmax, re-gather target row from gd_b (fp16), tail heads ----------------
__global__ void final_kernel(const float* __restrict__ pmax, const int* __restrict__ pidx, int nblocks,
                             const __half* __restrict__ gin, const int* __restrict__ rowstart,
                             const int* __restrict__ csr_src, const float* __restrict__ dis,
                             const float* __restrict__ W3, const float* __restrict__ b3,
                             const float* __restrict__ Wt, const float* __restrict__ bt,
                             const float* __restrict__ Wact, const float* __restrict__ bact,
                             float* __restrict__ out) {
    __shared__ float smax[256];
    __shared__ int sidx[256];
    __shared__ float part[8][F];
    __shared__ float hrow[F];
    __shared__ float ht[F];
    int tid = threadIdx.x;
    float best = -INFINITY; int bi = 0x7fffffff;
    for (int i = tid; i < nblocks; i += 256) {
        float v = pmax[i]; int ix = pidx[i];
        if (v > best || (v == best && ix < bi)) { best = v; bi = ix; }
    }
    smax[tid] = best; sidx[tid] = bi;
    __syncthreads();
    for (int st = 128; st > 0; st >>= 1) {
        if (tid < st) {
            float v2 = smax[tid + st]; int i2 = sidx[tid + st];
            if (v2 > smax[tid] || (v2 == smax[tid] && i2 < sidx[tid])) { smax[tid] = v2; sidx[tid] = i2; }
        }
        __syncthreads();
    }
    int target = sidx[0];
    int g = tid >> 5, f = tid & 31;
    int start = rowstart[target], end = rowstart[target + 1];
    float acc = 0.0f;
    for (int i = start + g; i < end; i += 8)
        acc += __half2float(gin[(size_t)csr_src[i] * F + f]);
    part[g][f] = acc;
    __syncthreads();
    if (tid < F) {
        float s = 0.0f;
#pragma unroll
        for (int gg = 0; gg < 8; gg++) s += part[gg][tid];
        hrow[tid] = dis[target] * s;
    }
    __syncthreads();
    if (tid < F) {
        float a = b3[tid];
#pragma unroll
        for (int k = 0; k < F; k++) a += hrow[k] * W3[k*F+tid];
        ht[tid] = a > 0.0f ? a : 0.0f;
    }
    __syncthreads();
    if (tid < 2) {
        float a = bt[tid];
#pragma unroll
        for (int k = 0; k < F; k++) a += ht[k] * Wt[k*2+tid];
        out[2 * N_NODES + tid] = a;
    } else if (tid < 11) {
        int j = tid - 2;
        float a = bact[j];
#pragma unroll
        for (int k = 0; k < F; k++) a += ht[k] * Wact[k*9+j];
        out[2 * N_NODES + 2 + j] = a;
    }
}

extern "C" void kernel_launch(void* const* d_in, const int* in_sizes, int n_in,
                              void* d_out, int out_size, void* d_ws, size_t ws_size,
                              hipStream_t stream) {
    const float* x  = (const float*)d_in[0];
    const int*   ei = (const int*)d_in[1];
    const int E = in_sizes[1] / 2;
    const int* row = ei;
    const int* col = ei + E;
    const float* W1 = (const float*)d_in[2];
    const float* b1 = (const float*)d_in[3];
    const float* W2 = (const float*)d_in[4];
    const float* b2 = (const float*)d_in[5];
    const float* W3 = (const float*)d_in[6];
    const float* b3 = (const float*)d_in[7];
    const float* Wd = (const float*)d_in[8];
    const float* bd = (const float*)d_in[9];
    const float* Wa = (const float*)d_in[10];
    const float* ba = (const float*)d_in[11];
    const float* Wt = (const float*)d_in[12];
    const float* bt = (const float*)d_in[13];
    const float* Wact = (const float*)d_in[14];
    const float* bact = (const float*)d_in[15];

    float* out = (float*)d_out;
    float* ws  = (float*)d_ws;

    // workspace layout (floats):
    //   dis [0,N) | xd [N,9N) | gd_a (half,16N fl) [17N,33N) | gd_b (half,16N fl) [33N,49N)
    //   storage (E u32 <= 16N slots, exact) aliases gd_b; dead before layer_mid writes gd_b
    //   ints from 49N: bucket_base[NB+1] | counts[NBLK*NB] | boff[NBLK*NB] |
    //     rowstart[N+1] | csr_src[E] | pmax[12500] | pidx[12500] | tot[NB]
    float*    dis      = ws;
    float*    xd       = ws + N_NODES;
    __half*   gd_a     = (__half*)(ws + (size_t)17 * N_NODES);
    __half*   gd_b     = (__half*)(ws + (size_t)33 * N_NODES);
    unsigned* storage  = (unsigned*)(ws + (size_t)33 * N_NODES);
    int*      bucket_base = (int*)(ws + (size_t)49 * N_NODES);    // NB+1
    int*      counts   = bucket_base + NB + 1;                    // NBLK*NB = 200064
    int*      boff     = counts + NBLK * NB;                      // 200064
    int*      rowstart = boff + NBLK * NB;                        // N+1
    int*      csr_src  = rowstart + N_NODES + 1;                  // E
    float*    pmax     = (float*)(csr_src + E);                   // 3125 used
    int*      pidx     = (int*)(pmax + 12500);                    // 3125 used
    int*      tot      = pidx + 12500;                            // NB

    const int B = 256;
    const int nb32 = (N_NODES + 31) / 32;          // 3125 (exact, no partial block)

    // ---- CSR build: 2-pass block-local counting sort, ZERO device atomics ----
    hist_kernel<<<NBLK, 1024, 0, stream>>>(col, counts, E);
    tot_kernel<<<(NB + 255) / 256, B, 0, stream>>>(counts, tot);
    offA_kernel<<<1, 1024, 0, stream>>>(tot, bucket_base, rowstart);
    offB_kernel<<<(NB + 255) / 256, B, 0, stream>>>(counts, bucket_base, boff);
    scatter_kernel<<<NBLK, 1024, 0, stream>>>(row, col, boff, storage, E);
    csr_build_kernel<<<NB, B, 0, stream>>>(storage, bucket_base, rowstart, csr_src, dis, x, xd, N_NODES);

    // ---- layer 1 (fused gather + W1 transform) ----
    layer1_fused<<<nb32, B, 0, stream>>>(xd, rowstart, csr_src, dis, W1, b1, gd_a, N_NODES);

    // ---- layer 2 (fused gather + transform, 8 lanes/node, idx-shfl + prefetch) ----
    layer_mid_fused<<<nb32, B, 0, stream>>>((const uint2*)gd_a, rowstart, csr_src, dis,
                                            W2, b2, (uint2*)gd_b, N_NODES, E);

    // ---- layer 3 + heads (fused, 8 lanes/node) ----
    layer_last_fused<<<nb32, B, 0, stream>>>((const uint2*)gd_b, rowstart, csr_src, dis,
                                             W3, b3, Wd, bd, Wa, ba, out, pmax, pidx, N_NODES, E);
    final_kernel<<<1, B, 0, stream>>>(pmax, pidx, nb32, gd_b, rowstart, csr_src, dis,
                                      W3, b3, Wt, bt, Wact, bact, out);
}